// Round 8
// baseline (491.541 us; speedup 1.0000x reference)
//
#include <hip/hip_runtime.h>
#include <hip/hip_bf16.h>
#include <stdint.h>

#define HID   128
#define DT    0.1f
#define NITER 10
#define RT    64           // rows (b,q pairs) per block
#define NT    256          // 4 waves
#define HSTR  136          // H row stride in bf16 elems (odd multiple of 16B)

typedef __attribute__((ext_vector_type(8))) short bf16x8;   // MFMA A/B frag
typedef __attribute__((ext_vector_type(4))) float f32x4;    // MFMA C/D frag
typedef __attribute__((ext_vector_type(2))) float f32x2;
typedef __attribute__((ext_vector_type(2))) unsigned int u32x2;
typedef __attribute__((ext_vector_type(4))) unsigned int u32x4;

struct alignas(16) Smem {
    uint16_t hA[RT * HSTR];     // activations [batch][hid] bf16
    uint16_t hB[RT * HSTR];     // ping-pong; start doubles as kk at L4 time
    uint16_t xb[RT * 8];        // X bf16 [row][8], cols 4..7 stay zero
    uint32_t w4f[4 * 64 * 4];   // W4 A-frags, [kt][lane] as uint4
    float    b1[HID], b2[HID], b3[HID];
};

__device__ __forceinline__ uint16_t f2bf(float f) {
    uint32_t u = __float_as_uint(f);
    return (uint16_t)((u + 0x7fffu + ((u >> 16) & 1u)) >> 16);
}

__device__ __forceinline__ uint32_t pk2(float a, float b) {
    __hip_bfloat162 h = __float22bfloat162_rn(float2{a, b});
    return *reinterpret_cast<uint32_t*>(&h);
}

// ---- guaranteed packed-fp32 (VOP3P, gfx90a+) ----
__device__ __forceinline__ f32x2 pk_add(f32x2 a, f32x2 b) {
    f32x2 d; asm("v_pk_add_f32 %0, %1, %2" : "=v"(d) : "v"(a), "v"(b)); return d;
}
__device__ __forceinline__ f32x2 pk_mul(f32x2 a, f32x2 b) {
    f32x2 d; asm("v_pk_mul_f32 %0, %1, %2" : "=v"(d) : "v"(a), "v"(b)); return d;
}
__device__ __forceinline__ f32x2 pk_fma(f32x2 a, f32x2 b, f32x2 c) {
    f32x2 d; asm("v_pk_fma_f32 %0, %1, %2, %3" : "=v"(d) : "v"(a), "v"(b), "v"(c)); return d;
}

// Two tanh via Pade[7/6], clamped to +/-3.5; ONE v_rcp per pair (common
// denominator): tanh(a),tanh(b) = (na*db, nb*da) * rcp(da*db). Full-rate
// math forced onto v_pk_*_f32. Err < 1e-5 + ~1e-6 (shared rcp) -- below
// bf16 rounding, so output-identical to exact tanh after bf16 quantize.
__device__ __forceinline__ uint32_t tanh2_bf16(float a, float b) {
    const f32x2 c378    = {378.f, 378.f};
    const f32x2 c17325  = {17325.f, 17325.f};
    const f32x2 c135135 = {135135.f, 135135.f};
    const f32x2 c28     = {28.f, 28.f};
    const f32x2 c3150   = {3150.f, 3150.f};
    const f32x2 c62370  = {62370.f, 62370.f};
    f32x2 x;
    x.x = __builtin_amdgcn_fmed3f(a, -3.5f, 3.5f);
    x.y = __builtin_amdgcn_fmed3f(b, -3.5f, 3.5f);
    f32x2 s = pk_mul(x, x);
    f32x2 n = pk_add(s, c378);
    n = pk_fma(n, s, c17325);
    n = pk_fma(n, s, c135135);
    n = pk_mul(n, x);
    f32x2 d = pk_fma(s, c28, c3150);
    d = pk_fma(d, s, c62370);
    d = pk_fma(d, s, c135135);
    float r = __builtin_amdgcn_rcpf(d.x * d.y);   // d >= 135135 > 0, dd ~ 2e10: safe
    f32x2 dsw = __builtin_shufflevector(d, d, 1, 0);
    f32x2 t = pk_mul(n, dsw);
    f32x2 rr = {r, r};
    f32x2 res = pk_mul(t, rr);
    __hip_bfloat162 h = __float22bfloat162_rn(float2{res.x, res.y});
    return *reinterpret_cast<uint32_t*>(&h);
}

// dst = tanh(src @ W + bias), transposed MFMA. Wave owns M-slice of 32
// (2 m-tiles), covers all 64 batch rows (4 n-tiles). Bias from LDS.
__device__ __forceinline__ void dense_mfma(
    const bf16x8 (&wf)[2][4], const float* __restrict__ bias,
    const uint16_t* __restrict__ src, uint16_t* __restrict__ dst,
    int w, int ln, int g)
{
    f32x4 acc[2][4];
    #pragma unroll
    for (int mt = 0; mt < 2; ++mt) {
        f32x4 bs = *(const f32x4*)&bias[w * 32 + mt * 16 + 4 * g];
        #pragma unroll
        for (int nt = 0; nt < 4; ++nt) acc[mt][nt] = bs;
    }
    #pragma unroll
    for (int kt = 0; kt < 4; ++kt) {
        bf16x8 bfr[4];
        #pragma unroll
        for (int nt = 0; nt < 4; ++nt)
            bfr[nt] = *(const bf16x8*)&src[(nt * 16 + ln) * HSTR + kt * 32 + 8 * g];
        #pragma unroll
        for (int mt = 0; mt < 2; ++mt)
            #pragma unroll
            for (int nt = 0; nt < 4; ++nt)
                acc[mt][nt] = __builtin_amdgcn_mfma_f32_16x16x32_bf16(wf[mt][kt], bfr[nt], acc[mt][nt], 0, 0, 0);
    }
    #pragma unroll
    for (int mt = 0; mt < 2; ++mt) {
        int hb = w * 32 + mt * 16 + 4 * g;
        #pragma unroll
        for (int nt = 0; nt < 4; ++nt) {
            int r = nt * 16 + ln;
            u32x2 p;
            p.x = tanh2_bf16(acc[mt][nt][0], acc[mt][nt][1]);
            p.y = tanh2_bf16(acc[mt][nt][2], acc[mt][nt][3]);
            *(u32x2*)&dst[r * HSTR + hb] = p;
        }
    }
}

__global__ __launch_bounds__(NT, 3) void pinn_irk_mfma(
    const float* __restrict__ x0g,
    const float* __restrict__ w1g, const float* __restrict__ b1g,
    const float* __restrict__ w2g, const float* __restrict__ b2g,
    const float* __restrict__ w3g, const float* __restrict__ b3g,
    const float* __restrict__ w4g, const float* __restrict__ b4g,
    const float* __restrict__ l1g, const float* __restrict__ l2g,
    const float* __restrict__ l3g, const float* __restrict__ l4g,
    const float* __restrict__ alg, const float* __restrict__ beg,
    float* __restrict__ outg)
{
    __shared__ Smem S;
    float* kkp = reinterpret_cast<float*>(S.hB);   // overlay: live only L4->combine
    const int t    = threadIdx.x;
    const int blk  = blockIdx.x;
    const int lane = t & 63;
    const int w    = t >> 6;        // wave 0..3: owns hid slice [w*32, w*32+32)
    const int ln   = lane & 15;
    const int g    = lane >> 4;     // quad
    const bool owner = (g == 0);
    const int r_own  = w * 16 + ln; // batch row owned by this lane (if owner)

    // ---- uniform params -> SGPRs ----
    const float L0 = l1g[0], L1v = l2g[0], L2v = l3g[0], L3v = l4g[0];
    const float B40 = b4g[0], B41 = b4g[1], B42 = b4g[2], B43 = b4g[3];

    // ---- stage biases / zero xb pad ----
    if (t < HID) { S.b1[t] = b1g[t]; S.b2[t] = b2g[t]; S.b3[t] = b3g[t]; }
    {   // zero cols 4..7 of xb (cols 0..3 written by owner lanes)
        int r = t >> 2, c = 4 + (t & 3);
        S.xb[r * 8 + c] = 0;
    }
    // ---- stage W4 A-frags into LDS: [kt][lane] ----
    {
        int kt = t >> 6, l = t & 63;
        int lns = l & 15, gs = l >> 4;
        uint32_t f[4];
        #pragma unroll
        for (int jj = 0; jj < 4; ++jj) {
            int k0 = kt * 32 + 8 * gs + 2 * jj;
            uint32_t lo = (lns < 4) ? (uint32_t)f2bf(w4g[k0 * 4 + lns]) : 0u;
            uint32_t hi = (lns < 4) ? (uint32_t)f2bf(w4g[(k0 + 1) * 4 + lns]) : 0u;
            f[jj] = lo | (hi << 16);
        }
        *(u32x4*)&S.w4f[t * 4] = (u32x4){f[0], f[1], f[2], f[3]};
    }

    // ---- owner-lane state: X0 / X in registers; init xb ----
    float X0r[4] = {0.f, 0.f, 0.f, 0.f};
    float Xr[4]  = {0.f, 0.f, 0.f, 0.f};
    if (owner) {
        const float* xp = x0g + (blk * (RT / 4) + (r_own >> 2)) * 4;
        #pragma unroll
        for (int c = 0; c < 4; ++c) { X0r[c] = xp[c]; Xr[c] = X0r[c]; }
        u32x2 p;
        p.x = pk2(Xr[0], Xr[1]);
        p.y = pk2(Xr[2], Xr[3]);
        *(u32x2*)&S.xb[r_own * 8] = p;
    }

    // ---- weight fragments W1/W2/W3 (M-slice of 32 per wave) ----
    // A-frag of W^T: lane (ln,g), elem j -> W[k=kt*32+8g+j][m=w*32+mt*16+ln]
    bf16x8 w1f[2], w2f[2][4], w3f[2][4];
    {
        const int mcol = w * 32 + ln;
        #pragma unroll
        for (int mt = 0; mt < 2; ++mt) {
            bf16x8 f1;
            #pragma unroll
            for (int j = 0; j < 8; ++j) {
                int k = 8 * g + j;
                float v = (k < 4) ? w1g[k * HID + mcol + mt * 16] : 0.0f;
                f1[j] = (short)f2bf(v);
            }
            w1f[mt] = f1;
            #pragma unroll
            for (int kt = 0; kt < 4; ++kt) {
                bf16x8 f2, f3;
                #pragma unroll
                for (int j = 0; j < 8; ++j) {
                    int k = kt * 32 + 8 * g + j;
                    f2[j] = (short)f2bf(w2g[k * HID + mcol + mt * 16]);
                    f3[j] = (short)f2bf(w3g[k * HID + mcol + mt * 16]);
                }
                w2f[mt][kt] = f2;
                w3f[mt][kt] = f3;
            }
        }
    }
    __syncthreads();

    #pragma unroll 1
    for (int it = 0; it < NITER; ++it) {
        // ---- L1: hA = tanh(X @ W1 + b1), K padded 4->32 ----
        {
            f32x4 acc[2][4];
            #pragma unroll
            for (int mt = 0; mt < 2; ++mt) {
                f32x4 bs = *(const f32x4*)&S.b1[w * 32 + mt * 16 + 4 * g];
                #pragma unroll
                for (int nt = 0; nt < 4; ++nt) acc[mt][nt] = bs;
            }
            bf16x8 bfr[4];
            #pragma unroll
            for (int nt = 0; nt < 4; ++nt) bfr[nt] = (bf16x8){0,0,0,0,0,0,0,0};
            if (g == 0) {
                #pragma unroll
                for (int nt = 0; nt < 4; ++nt)
                    bfr[nt] = *(const bf16x8*)&S.xb[(nt * 16 + ln) * 8];
            }
            #pragma unroll
            for (int mt = 0; mt < 2; ++mt)
                #pragma unroll
                for (int nt = 0; nt < 4; ++nt)
                    acc[mt][nt] = __builtin_amdgcn_mfma_f32_16x16x32_bf16(w1f[mt], bfr[nt], acc[mt][nt], 0, 0, 0);
            #pragma unroll
            for (int mt = 0; mt < 2; ++mt) {
                int hb = w * 32 + mt * 16 + 4 * g;
                #pragma unroll
                for (int nt = 0; nt < 4; ++nt) {
                    int r = nt * 16 + ln;
                    u32x2 p;
                    p.x = tanh2_bf16(acc[mt][nt][0], acc[mt][nt][1]);
                    p.y = tanh2_bf16(acc[mt][nt][2], acc[mt][nt][3]);
                    *(u32x2*)&S.hA[r * HSTR + hb] = p;
                }
            }
        }
        __syncthreads();

        // ---- L2 ----
        dense_mfma(w2f, S.b2, S.hA, S.hB, w, ln, g);
        __syncthreads();

        // ---- L3 ----
        dense_mfma(w3f, S.b3, S.hB, S.hA, w, ln, g);
        __syncthreads();

        // ---- L4 + K update + X update (owner lanes); kk overlays hB (dead here) ----
        {
            f32x4 acc = (f32x4){0.f, 0.f, 0.f, 0.f};
            #pragma unroll
            for (int kt = 0; kt < 4; ++kt) {
                bf16x8 wfr = *(const bf16x8*)&S.w4f[(kt * 64 + lane) * 4];
                bf16x8 bfr = *(const bf16x8*)&S.hA[r_own * HSTR + kt * 32 + 8 * g];
                acc = __builtin_amdgcn_mfma_f32_16x16x32_bf16(wfr, bfr, acc, 0, 0, 0);
            }
            if (owner) {
                float h0 = acc[0] + B40, h1 = acc[1] + B41;
                float h2 = acc[2] + B42, h3 = acc[3] + B43;
                float kv0 = -L0 * h2 - L1v * Xr[2];
                float kv1 = -L0 * h3 - L1v * Xr[3];
                float kv2 =  L2v * h0 + L3v * Xr[0];
                float kv3 =  L2v * h1 + L3v * Xr[1];
                *(f32x4*)&kkp[r_own * 4] = (f32x4){kv0, kv1, kv2, kv3};
                #pragma unroll
                for (int c = 0; c < 4; ++c) {
                    float s = kv0 * alg[c] + kv1 * alg[4 + c]
                            + kv2 * alg[8 + c] + kv3 * alg[12 + c];
                    Xr[c] = fmaf(DT, s, X0r[c]);
                }
                u32x2 p;
                p.x = pk2(Xr[0], Xr[1]);
                p.y = pk2(Xr[2], Xr[3]);
                *(u32x2*)&S.xb[r_own * 8] = p;
            }
        }
        __syncthreads();
    }

    // ---- final combine: X1 = X0 + dt * sum_q beta_q K[:,q,:] ----
    if (t < RT) {
        int bb = t >> 2, i = t & 3;
        float s = beg[0] * kkp[(bb * 4 + 0) * 4 + i]
                + beg[1] * kkp[(bb * 4 + 1) * 4 + i]
                + beg[2] * kkp[(bb * 4 + 2) * 4 + i]
                + beg[3] * kkp[(bb * 4 + 3) * 4 + i];
        int bglob = blk * (RT / 4) + bb;
        outg[bglob * 4 + i] = x0g[bglob * 4 + i] + DT * s;
    }
}

extern "C" void kernel_launch(void* const* d_in, const int* in_sizes, int n_in,
                              void* d_out, int out_size, void* d_ws, size_t ws_size,
                              hipStream_t stream) {
    (void)in_sizes; (void)n_in; (void)d_ws; (void)ws_size; (void)out_size;

    const int n_rows = 65536 * 4;        // B * Q
    dim3 grid(n_rows / RT);              // 4096
    dim3 block(NT);

    pinn_irk_mfma<<<grid, block, 0, stream>>>(
        (const float*)d_in[0],
        (const float*)d_in[1],  (const float*)d_in[2],
        (const float*)d_in[3],  (const float*)d_in[4],
        (const float*)d_in[5],  (const float*)d_in[6],
        (const float*)d_in[7],  (const float*)d_in[8],
        (const float*)d_in[9],  (const float*)d_in[10],
        (const float*)d_in[11], (const float*)d_in[12],
        (const float*)d_in[13], (const float*)d_in[14],
        (float*)d_out);
}

// Round 9
// 463.229 us; speedup vs baseline: 1.0611x; 1.0611x over previous
//
#include <hip/hip_runtime.h>
#include <hip/hip_bf16.h>
#include <stdint.h>

#define HID   128
#define DT    0.1f
#define NITER 10
#define RT    32           // rows (b,q pairs) per block (halved for occupancy)
#define NT    256          // 4 waves
#define HSTR  136          // H row stride in bf16 elems (odd multiple of 16B)

typedef __attribute__((ext_vector_type(8))) short bf16x8;   // MFMA A/B frag
typedef __attribute__((ext_vector_type(4))) float f32x4;    // MFMA C/D frag
typedef __attribute__((ext_vector_type(2))) unsigned int u32x2;
typedef __attribute__((ext_vector_type(4))) unsigned int u32x4;

struct alignas(16) Smem {
    uint16_t hA[RT * HSTR];     // activations [batch][hid] bf16 (8704 B)
    uint16_t hB[RT * HSTR];     // ping-pong; start doubles as kk at L4 time
    uint16_t xb[RT * 8];        // X bf16 [row][8], cols 4..7 stay zero
    uint32_t w4f[4 * 64 * 4];   // W4 A-frags, [kt][lane] as uint4 (4096 B)
    float    b1[HID], b2[HID], b3[HID];
};                              // ~23.5 KB -> 4 blocks/CU (wave-slot limited)

__device__ __forceinline__ uint16_t f2bf(float f) {
    uint32_t u = __float_as_uint(f);
    return (uint16_t)((u + 0x7fffu + ((u >> 16) & 1u)) >> 16);
}

__device__ __forceinline__ uint32_t pk2(float a, float b) {
    __hip_bfloat162 h = __float22bfloat162_rn(float2{a, b});
    return *reinterpret_cast<uint32_t*>(&h);
}

// Proven-fastest tanh (R5, 385us): exp2 + rcp, 2 transcendental + 4 full-rate.
__device__ __forceinline__ float tanh_fast(float x) {
    float xc = fminf(fmaxf(x, -9.0f), 9.0f);
    float e  = __builtin_amdgcn_exp2f(xc * 2.885390081777927f);  // e^{2x}
    return fmaf(-2.0f, __builtin_amdgcn_rcpf(e + 1.0f), 1.0f);
}

// dst = tanh(src @ W + bias), transposed MFMA. Wave owns M-slice of 32
// (2 m-tiles), covers all 32 batch rows (2 n-tiles). Bias from LDS.
__device__ __forceinline__ void dense_mfma(
    const bf16x8 (&wf)[2][4], const float* __restrict__ bias,
    const uint16_t* __restrict__ src, uint16_t* __restrict__ dst,
    int w, int ln, int g)
{
    f32x4 acc[2][2];
    #pragma unroll
    for (int mt = 0; mt < 2; ++mt) {
        f32x4 bs = *(const f32x4*)&bias[w * 32 + mt * 16 + 4 * g];
        #pragma unroll
        for (int nt = 0; nt < 2; ++nt) acc[mt][nt] = bs;
    }
    #pragma unroll
    for (int kt = 0; kt < 4; ++kt) {
        bf16x8 bfr[2];
        #pragma unroll
        for (int nt = 0; nt < 2; ++nt)
            bfr[nt] = *(const bf16x8*)&src[(nt * 16 + ln) * HSTR + kt * 32 + 8 * g];
        #pragma unroll
        for (int mt = 0; mt < 2; ++mt)
            #pragma unroll
            for (int nt = 0; nt < 2; ++nt)
                acc[mt][nt] = __builtin_amdgcn_mfma_f32_16x16x32_bf16(wf[mt][kt], bfr[nt], acc[mt][nt], 0, 0, 0);
    }
    #pragma unroll
    for (int mt = 0; mt < 2; ++mt) {
        int hb = w * 32 + mt * 16 + 4 * g;
        #pragma unroll
        for (int nt = 0; nt < 2; ++nt) {
            int r = nt * 16 + ln;
            u32x2 p;
            p.x = pk2(tanh_fast(acc[mt][nt][0]), tanh_fast(acc[mt][nt][1]));
            p.y = pk2(tanh_fast(acc[mt][nt][2]), tanh_fast(acc[mt][nt][3]));
            *(u32x2*)&dst[r * HSTR + hb] = p;
        }
    }
}

__global__ __launch_bounds__(NT, 4) void pinn_irk_mfma(
    const float* __restrict__ x0g,
    const float* __restrict__ w1g, const float* __restrict__ b1g,
    const float* __restrict__ w2g, const float* __restrict__ b2g,
    const float* __restrict__ w3g, const float* __restrict__ b3g,
    const float* __restrict__ w4g, const float* __restrict__ b4g,
    const float* __restrict__ l1g, const float* __restrict__ l2g,
    const float* __restrict__ l3g, const float* __restrict__ l4g,
    const float* __restrict__ alg, const float* __restrict__ beg,
    float* __restrict__ outg)
{
    __shared__ Smem S;
    float* kkp = reinterpret_cast<float*>(S.hB);   // overlay: live only L4->combine
    const int t    = threadIdx.x;
    const int blk  = blockIdx.x;
    const int lane = t & 63;
    const int w    = t >> 6;        // wave 0..3: owns hid slice [w*32, w*32+32)
    const int ln   = lane & 15;
    const int g    = lane >> 4;     // quad
    const bool l4wave = (w < 2);    // waves 0-1 handle the 32 rows in L4 phase
    const bool owner  = l4wave && (g == 0);
    const int r_own   = w * 16 + ln;  // batch row owned (valid when l4wave)

    // ---- uniform params -> SGPRs ----
    const float L0 = l1g[0], L1v = l2g[0], L2v = l3g[0], L3v = l4g[0];
    const float B40 = b4g[0], B41 = b4g[1], B42 = b4g[2], B43 = b4g[3];

    // ---- stage biases / zero xb pad ----
    if (t < HID) { S.b1[t] = b1g[t]; S.b2[t] = b2g[t]; S.b3[t] = b3g[t]; }
    if (t < RT * 4) {   // zero cols 4..7 of xb
        int r = t >> 2, c = 4 + (t & 3);
        S.xb[r * 8 + c] = 0;
    }
    // ---- stage W4 A-frags into LDS: [kt][lane] ----
    {
        int kt = t >> 6, l = t & 63;
        int lns = l & 15, gs = l >> 4;
        uint32_t f[4];
        #pragma unroll
        for (int jj = 0; jj < 4; ++jj) {
            int k0 = kt * 32 + 8 * gs + 2 * jj;
            uint32_t lo = (lns < 4) ? (uint32_t)f2bf(w4g[k0 * 4 + lns]) : 0u;
            uint32_t hi = (lns < 4) ? (uint32_t)f2bf(w4g[(k0 + 1) * 4 + lns]) : 0u;
            f[jj] = lo | (hi << 16);
        }
        *(u32x4*)&S.w4f[t * 4] = (u32x4){f[0], f[1], f[2], f[3]};
    }

    // ---- owner-lane state: X0 / X in registers; init xb ----
    float X0r[4] = {0.f, 0.f, 0.f, 0.f};
    float Xr[4]  = {0.f, 0.f, 0.f, 0.f};
    if (owner) {
        const float* xp = x0g + (blk * (RT / 4) + (r_own >> 2)) * 4;
        #pragma unroll
        for (int c = 0; c < 4; ++c) { X0r[c] = xp[c]; Xr[c] = X0r[c]; }
        u32x2 p;
        p.x = pk2(Xr[0], Xr[1]);
        p.y = pk2(Xr[2], Xr[3]);
        *(u32x2*)&S.xb[r_own * 8] = p;
    }

    // ---- weight fragments W1/W2/W3 (M-slice of 32 per wave) ----
    // A-frag of W^T: lane (ln,g), elem j -> W[k=kt*32+8g+j][m=w*32+mt*16+ln]
    bf16x8 w1f[2], w2f[2][4], w3f[2][4];
    {
        const int mcol = w * 32 + ln;
        #pragma unroll
        for (int mt = 0; mt < 2; ++mt) {
            bf16x8 f1;
            #pragma unroll
            for (int j = 0; j < 8; ++j) {
                int k = 8 * g + j;
                float v = (k < 4) ? w1g[k * HID + mcol + mt * 16] : 0.0f;
                f1[j] = (short)f2bf(v);
            }
            w1f[mt] = f1;
            #pragma unroll
            for (int kt = 0; kt < 4; ++kt) {
                bf16x8 f2, f3;
                #pragma unroll
                for (int j = 0; j < 8; ++j) {
                    int k = kt * 32 + 8 * g + j;
                    f2[j] = (short)f2bf(w2g[k * HID + mcol + mt * 16]);
                    f3[j] = (short)f2bf(w3g[k * HID + mcol + mt * 16]);
                }
                w2f[mt][kt] = f2;
                w3f[mt][kt] = f3;
            }
        }
    }
    __syncthreads();

    #pragma unroll 1
    for (int it = 0; it < NITER; ++it) {
        // ---- L1: hA = tanh(X @ W1 + b1), K padded 4->32 ----
        {
            f32x4 acc[2][2];
            #pragma unroll
            for (int mt = 0; mt < 2; ++mt) {
                f32x4 bs = *(const f32x4*)&S.b1[w * 32 + mt * 16 + 4 * g];
                #pragma unroll
                for (int nt = 0; nt < 2; ++nt) acc[mt][nt] = bs;
            }
            bf16x8 bfr[2];
            #pragma unroll
            for (int nt = 0; nt < 2; ++nt) bfr[nt] = (bf16x8){0,0,0,0,0,0,0,0};
            if (g == 0) {
                #pragma unroll
                for (int nt = 0; nt < 2; ++nt)
                    bfr[nt] = *(const bf16x8*)&S.xb[(nt * 16 + ln) * 8];
            }
            #pragma unroll
            for (int mt = 0; mt < 2; ++mt)
                #pragma unroll
                for (int nt = 0; nt < 2; ++nt)
                    acc[mt][nt] = __builtin_amdgcn_mfma_f32_16x16x32_bf16(w1f[mt], bfr[nt], acc[mt][nt], 0, 0, 0);
            #pragma unroll
            for (int mt = 0; mt < 2; ++mt) {
                int hb = w * 32 + mt * 16 + 4 * g;
                #pragma unroll
                for (int nt = 0; nt < 2; ++nt) {
                    int r = nt * 16 + ln;
                    u32x2 p;
                    p.x = pk2(tanh_fast(acc[mt][nt][0]), tanh_fast(acc[mt][nt][1]));
                    p.y = pk2(tanh_fast(acc[mt][nt][2]), tanh_fast(acc[mt][nt][3]));
                    *(u32x2*)&S.hA[r * HSTR + hb] = p;
                }
            }
        }
        __syncthreads();

        // ---- L2 ----
        dense_mfma(w2f, S.b2, S.hA, S.hB, w, ln, g);
        __syncthreads();

        // ---- L3 ----
        dense_mfma(w3f, S.b3, S.hB, S.hA, w, ln, g);
        __syncthreads();

        // ---- L4 + K update + X update (waves 0-1 only); kk overlays hB ----
        if (l4wave) {
            f32x4 acc = (f32x4){0.f, 0.f, 0.f, 0.f};
            #pragma unroll
            for (int kt = 0; kt < 4; ++kt) {
                bf16x8 wfr = *(const bf16x8*)&S.w4f[(kt * 64 + lane) * 4];
                bf16x8 bfr = *(const bf16x8*)&S.hA[r_own * HSTR + kt * 32 + 8 * g];
                acc = __builtin_amdgcn_mfma_f32_16x16x32_bf16(wfr, bfr, acc, 0, 0, 0);
            }
            if (owner) {
                float h0 = acc[0] + B40, h1 = acc[1] + B41;
                float h2 = acc[2] + B42, h3 = acc[3] + B43;
                float kv0 = -L0 * h2 - L1v * Xr[2];
                float kv1 = -L0 * h3 - L1v * Xr[3];
                float kv2 =  L2v * h0 + L3v * Xr[0];
                float kv3 =  L2v * h1 + L3v * Xr[1];
                *(f32x4*)&kkp[r_own * 4] = (f32x4){kv0, kv1, kv2, kv3};
                #pragma unroll
                for (int c = 0; c < 4; ++c) {
                    float s = kv0 * alg[c] + kv1 * alg[4 + c]
                            + kv2 * alg[8 + c] + kv3 * alg[12 + c];
                    Xr[c] = fmaf(DT, s, X0r[c]);
                }
                u32x2 p;
                p.x = pk2(Xr[0], Xr[1]);
                p.y = pk2(Xr[2], Xr[3]);
                *(u32x2*)&S.xb[r_own * 8] = p;
            }
        }
        __syncthreads();
    }

    // ---- final combine: X1 = X0 + dt * sum_q beta_q K[:,q,:] ----
    if (t < RT) {
        int bb = t >> 2, i = t & 3;
        float s = beg[0] * kkp[(bb * 4 + 0) * 4 + i]
                + beg[1] * kkp[(bb * 4 + 1) * 4 + i]
                + beg[2] * kkp[(bb * 4 + 2) * 4 + i]
                + beg[3] * kkp[(bb * 4 + 3) * 4 + i];
        int bglob = blk * (RT / 4) + bb;
        outg[bglob * 4 + i] = x0g[bglob * 4 + i] + DT * s;
    }
}

extern "C" void kernel_launch(void* const* d_in, const int* in_sizes, int n_in,
                              void* d_out, int out_size, void* d_ws, size_t ws_size,
                              hipStream_t stream) {
    (void)in_sizes; (void)n_in; (void)d_ws; (void)ws_size; (void)out_size;

    const int n_rows = 65536 * 4;        // B * Q
    dim3 grid(n_rows / RT);              // 8192
    dim3 block(NT);

    pinn_irk_mfma<<<grid, block, 0, stream>>>(
        (const float*)d_in[0],
        (const float*)d_in[1],  (const float*)d_in[2],
        (const float*)d_in[3],  (const float*)d_in[4],
        (const float*)d_in[5],  (const float*)d_in[6],
        (const float*)d_in[7],  (const float*)d_in[8],
        (const float*)d_in[9],  (const float*)d_in[10],
        (const float*)d_in[11], (const float*)d_in[12],
        (const float*)d_in[13], (const float*)d_in[14],
        (float*)d_out);
}

// Round 10
// 410.818 us; speedup vs baseline: 1.1965x; 1.1276x over previous
//
#include <hip/hip_runtime.h>
#include <hip/hip_bf16.h>
#include <stdint.h>

#define HID   128
#define DT    0.1f
#define NITER 10
#define RT    64           // rows (b,q pairs) per block
#define NT    256          // 4 waves
#define HSTR  136          // H row stride in bf16 elems (odd multiple of 16B)
#define KSC   2.885390081777927f   // 2/ln2: folded into W1/W2/W3/b1/b2/b3

typedef __attribute__((ext_vector_type(8))) short bf16x8;   // MFMA A/B frag
typedef __attribute__((ext_vector_type(4))) float f32x4;    // MFMA C/D frag
typedef __attribute__((ext_vector_type(2))) unsigned int u32x2;
typedef __attribute__((ext_vector_type(4))) unsigned int u32x4;

struct alignas(16) Smem {
    uint16_t hA[RT * HSTR];     // activations [batch][hid] bf16
    uint16_t hB[RT * HSTR];     // ping-pong; start doubles as kk at L4 time
    uint16_t xb[RT * 8];        // X bf16 [row][8], cols 4..7 stay zero
    uint32_t w4f[4 * 64 * 4];   // W4 A-frags, [kt][lane] as uint4
    float    b1[HID], b2[HID], b3[HID];   // pre-scaled by KSC
};

__device__ __forceinline__ uint16_t f2bf(float f) {
    uint32_t u = __float_as_uint(f);
    return (uint16_t)((u + 0x7fffu + ((u >> 16) & 1u)) >> 16);
}

__device__ __forceinline__ uint32_t pk2(float a, float b) {
    __hip_bfloat162 h = __float22bfloat162_rn(float2{a, b});
    return *reinterpret_cast<uint32_t*>(&h);
}

// Two tanh with ONE v_rcp, inputs PRE-SCALED by 2/ln2 (scale folded into
// weights/biases):  tanh = 1 - 2/(exp2(z)+1),  z = 2x/ln2.
// Shared rcp: r = rcp(da*db); 2/da = 2*db*r.  Scalar ops only.
// Clamp +/-26 (== x +/- 9) keeps da*db finite so the partner value never
// sees inf*0 = NaN.  Error ~1e-7 << bf16 rounding.
__device__ __forceinline__ uint32_t tanh2_bf16(float a, float b) {
    float ca = __builtin_amdgcn_fmed3f(a, -26.0f, 26.0f);
    float cb = __builtin_amdgcn_fmed3f(b, -26.0f, 26.0f);
    float ea = __builtin_amdgcn_exp2f(ca);
    float eb = __builtin_amdgcn_exp2f(cb);
    float da = ea + 1.0f;
    float db = eb + 1.0f;
    float r  = __builtin_amdgcn_rcpf(da * db);
    float ma = db * r;                    // = 1/da
    float mb = da * r;                    // = 1/db
    float ta = fmaf(-2.0f, ma, 1.0f);
    float tb = fmaf(-2.0f, mb, 1.0f);
    __hip_bfloat162 h = __float22bfloat162_rn(float2{ta, tb});
    return *reinterpret_cast<uint32_t*>(&h);
}

// dst = tanh(src @ W + bias), transposed MFMA. Wave owns M-slice of 32
// (2 m-tiles), covers all 64 batch rows (4 n-tiles). Bias from LDS.
// W and bias pre-scaled by KSC.
__device__ __forceinline__ void dense_mfma(
    const bf16x8 (&wf)[2][4], const float* __restrict__ bias,
    const uint16_t* __restrict__ src, uint16_t* __restrict__ dst,
    int w, int ln, int g)
{
    f32x4 acc[2][4];
    #pragma unroll
    for (int mt = 0; mt < 2; ++mt) {
        f32x4 bs = *(const f32x4*)&bias[w * 32 + mt * 16 + 4 * g];
        #pragma unroll
        for (int nt = 0; nt < 4; ++nt) acc[mt][nt] = bs;
    }
    #pragma unroll
    for (int kt = 0; kt < 4; ++kt) {
        bf16x8 bfr[4];
        #pragma unroll
        for (int nt = 0; nt < 4; ++nt)
            bfr[nt] = *(const bf16x8*)&src[(nt * 16 + ln) * HSTR + kt * 32 + 8 * g];
        #pragma unroll
        for (int mt = 0; mt < 2; ++mt)
            #pragma unroll
            for (int nt = 0; nt < 4; ++nt)
                acc[mt][nt] = __builtin_amdgcn_mfma_f32_16x16x32_bf16(wf[mt][kt], bfr[nt], acc[mt][nt], 0, 0, 0);
    }
    #pragma unroll
    for (int mt = 0; mt < 2; ++mt) {
        int hb = w * 32 + mt * 16 + 4 * g;
        #pragma unroll
        for (int nt = 0; nt < 4; ++nt) {
            int r = nt * 16 + ln;
            u32x2 p;
            p.x = tanh2_bf16(acc[mt][nt][0], acc[mt][nt][1]);
            p.y = tanh2_bf16(acc[mt][nt][2], acc[mt][nt][3]);
            *(u32x2*)&dst[r * HSTR + hb] = p;
        }
    }
}

__global__ __launch_bounds__(NT, 3) void pinn_irk_mfma(
    const float* __restrict__ x0g,
    const float* __restrict__ w1g, const float* __restrict__ b1g,
    const float* __restrict__ w2g, const float* __restrict__ b2g,
    const float* __restrict__ w3g, const float* __restrict__ b3g,
    const float* __restrict__ w4g, const float* __restrict__ b4g,
    const float* __restrict__ l1g, const float* __restrict__ l2g,
    const float* __restrict__ l3g, const float* __restrict__ l4g,
    const float* __restrict__ alg, const float* __restrict__ beg,
    float* __restrict__ outg)
{
    __shared__ Smem S;
    float* kkp = reinterpret_cast<float*>(S.hB);   // overlay: live only L4->combine
    const int t    = threadIdx.x;
    const int blk  = blockIdx.x;
    const int lane = t & 63;
    const int w    = t >> 6;        // wave 0..3: owns hid slice [w*32, w*32+32)
    const int ln   = lane & 15;
    const int g    = lane >> 4;     // quad
    const bool owner = (g == 0);
    const int r_own  = w * 16 + ln; // batch row owned by this lane (if owner)

    // ---- uniform params -> SGPRs ----
    const float L0 = l1g[0], L1v = l2g[0], L2v = l3g[0], L3v = l4g[0];
    const float B40 = b4g[0], B41 = b4g[1], B42 = b4g[2], B43 = b4g[3];

    // ---- stage biases (pre-scaled) / zero xb pad ----
    if (t < HID) {
        S.b1[t] = b1g[t] * KSC;
        S.b2[t] = b2g[t] * KSC;
        S.b3[t] = b3g[t] * KSC;
    }
    {   // zero cols 4..7 of xb (cols 0..3 written by owner lanes)
        int r = t >> 2, c = 4 + (t & 3);
        S.xb[r * 8 + c] = 0;
    }
    // ---- stage W4 A-frags into LDS: [kt][lane] (NOT scaled) ----
    {
        int kt = t >> 6, l = t & 63;
        int lns = l & 15, gs = l >> 4;
        uint32_t f[4];
        #pragma unroll
        for (int jj = 0; jj < 4; ++jj) {
            int k0 = kt * 32 + 8 * gs + 2 * jj;
            uint32_t lo = (lns < 4) ? (uint32_t)f2bf(w4g[k0 * 4 + lns]) : 0u;
            uint32_t hi = (lns < 4) ? (uint32_t)f2bf(w4g[(k0 + 1) * 4 + lns]) : 0u;
            f[jj] = lo | (hi << 16);
        }
        *(u32x4*)&S.w4f[t * 4] = (u32x4){f[0], f[1], f[2], f[3]};
    }

    // ---- owner-lane state: X0 / X in registers; init xb ----
    float X0r[4] = {0.f, 0.f, 0.f, 0.f};
    float Xr[4]  = {0.f, 0.f, 0.f, 0.f};
    if (owner) {
        const float* xp = x0g + (blk * (RT / 4) + (r_own >> 2)) * 4;
        #pragma unroll
        for (int c = 0; c < 4; ++c) { X0r[c] = xp[c]; Xr[c] = X0r[c]; }
        u32x2 p;
        p.x = pk2(Xr[0], Xr[1]);
        p.y = pk2(Xr[2], Xr[3]);
        *(u32x2*)&S.xb[r_own * 8] = p;
    }

    // ---- weight fragments W1/W2/W3 (M-slice of 32 per wave), PRE-SCALED ----
    // A-frag of W^T: lane (ln,g), elem j -> W[k=kt*32+8g+j][m=w*32+mt*16+ln]
    bf16x8 w1f[2], w2f[2][4], w3f[2][4];
    {
        const int mcol = w * 32 + ln;
        #pragma unroll
        for (int mt = 0; mt < 2; ++mt) {
            bf16x8 f1;
            #pragma unroll
            for (int j = 0; j < 8; ++j) {
                int k = 8 * g + j;
                float v = (k < 4) ? w1g[k * HID + mcol + mt * 16] * KSC : 0.0f;
                f1[j] = (short)f2bf(v);
            }
            w1f[mt] = f1;
            #pragma unroll
            for (int kt = 0; kt < 4; ++kt) {
                bf16x8 f2, f3;
                #pragma unroll
                for (int j = 0; j < 8; ++j) {
                    int k = kt * 32 + 8 * g + j;
                    f2[j] = (short)f2bf(w2g[k * HID + mcol + mt * 16] * KSC);
                    f3[j] = (short)f2bf(w3g[k * HID + mcol + mt * 16] * KSC);
                }
                w2f[mt][kt] = f2;
                w3f[mt][kt] = f3;
            }
        }
    }
    __syncthreads();

    #pragma unroll 1
    for (int it = 0; it < NITER; ++it) {
        // ---- L1: hA = tanh(X @ W1 + b1), K padded 4->32 ----
        {
            f32x4 acc[2][4];
            #pragma unroll
            for (int mt = 0; mt < 2; ++mt) {
                f32x4 bs = *(const f32x4*)&S.b1[w * 32 + mt * 16 + 4 * g];
                #pragma unroll
                for (int nt = 0; nt < 4; ++nt) acc[mt][nt] = bs;
            }
            bf16x8 bfr[4];
            #pragma unroll
            for (int nt = 0; nt < 4; ++nt) bfr[nt] = (bf16x8){0,0,0,0,0,0,0,0};
            if (g == 0) {
                #pragma unroll
                for (int nt = 0; nt < 4; ++nt)
                    bfr[nt] = *(const bf16x8*)&S.xb[(nt * 16 + ln) * 8];
            }
            #pragma unroll
            for (int mt = 0; mt < 2; ++mt)
                #pragma unroll
                for (int nt = 0; nt < 4; ++nt)
                    acc[mt][nt] = __builtin_amdgcn_mfma_f32_16x16x32_bf16(w1f[mt], bfr[nt], acc[mt][nt], 0, 0, 0);
            #pragma unroll
            for (int mt = 0; mt < 2; ++mt) {
                int hb = w * 32 + mt * 16 + 4 * g;
                #pragma unroll
                for (int nt = 0; nt < 4; ++nt) {
                    int r = nt * 16 + ln;
                    u32x2 p;
                    p.x = tanh2_bf16(acc[mt][nt][0], acc[mt][nt][1]);
                    p.y = tanh2_bf16(acc[mt][nt][2], acc[mt][nt][3]);
                    *(u32x2*)&S.hA[r * HSTR + hb] = p;
                }
            }
        }
        __syncthreads();

        // ---- L2 ----
        dense_mfma(w2f, S.b2, S.hA, S.hB, w, ln, g);
        __syncthreads();

        // ---- L3 ----
        dense_mfma(w3f, S.b3, S.hB, S.hA, w, ln, g);
        __syncthreads();

        // ---- L4 + K update + X update (owner lanes); kk overlays hB ----
        {
            f32x4 acc = (f32x4){0.f, 0.f, 0.f, 0.f};
            #pragma unroll
            for (int kt = 0; kt < 4; ++kt) {
                bf16x8 wfr = *(const bf16x8*)&S.w4f[(kt * 64 + lane) * 4];
                bf16x8 bfr = *(const bf16x8*)&S.hA[r_own * HSTR + kt * 32 + 8 * g];
                acc = __builtin_amdgcn_mfma_f32_16x16x32_bf16(wfr, bfr, acc, 0, 0, 0);
            }
            if (owner) {
                float h0 = acc[0] + B40, h1 = acc[1] + B41;
                float h2 = acc[2] + B42, h3 = acc[3] + B43;
                float kv0 = -L0 * h2 - L1v * Xr[2];
                float kv1 = -L0 * h3 - L1v * Xr[3];
                float kv2 =  L2v * h0 + L3v * Xr[0];
                float kv3 =  L2v * h1 + L3v * Xr[1];
                *(f32x4*)&kkp[r_own * 4] = (f32x4){kv0, kv1, kv2, kv3};
                #pragma unroll
                for (int c = 0; c < 4; ++c) {
                    float s = kv0 * alg[c] + kv1 * alg[4 + c]
                            + kv2 * alg[8 + c] + kv3 * alg[12 + c];
                    Xr[c] = fmaf(DT, s, X0r[c]);
                }
                u32x2 p;
                p.x = pk2(Xr[0], Xr[1]);
                p.y = pk2(Xr[2], Xr[3]);
                *(u32x2*)&S.xb[r_own * 8] = p;
            }
        }
        __syncthreads();
    }

    // ---- final combine: X1 = X0 + dt * sum_q beta_q K[:,q,:] ----
    if (t < RT) {
        int bb = t >> 2, i = t & 3;
        float s = beg[0] * kkp[(bb * 4 + 0) * 4 + i]
                + beg[1] * kkp[(bb * 4 + 1) * 4 + i]
                + beg[2] * kkp[(bb * 4 + 2) * 4 + i]
                + beg[3] * kkp[(bb * 4 + 3) * 4 + i];
        int bglob = blk * (RT / 4) + bb;
        outg[bglob * 4 + i] = x0g[bglob * 4 + i] + DT * s;
    }
}

extern "C" void kernel_launch(void* const* d_in, const int* in_sizes, int n_in,
                              void* d_out, int out_size, void* d_ws, size_t ws_size,
                              hipStream_t stream) {
    (void)in_sizes; (void)n_in; (void)d_ws; (void)ws_size; (void)out_size;

    const int n_rows = 65536 * 4;        // B * Q
    dim3 grid(n_rows / RT);              // 4096
    dim3 block(NT);

    pinn_irk_mfma<<<grid, block, 0, stream>>>(
        (const float*)d_in[0],
        (const float*)d_in[1],  (const float*)d_in[2],
        (const float*)d_in[3],  (const float*)d_in[4],
        (const float*)d_in[5],  (const float*)d_in[6],
        (const float*)d_in[7],  (const float*)d_in[8],
        (const float*)d_in[9],  (const float*)d_in[10],
        (const float*)d_in[11], (const float*)d_in[12],
        (const float*)d_in[13], (const float*)d_in[14],
        (float*)d_out);
}